// Round 12
// baseline (328.598 us; speedup 1.0000x reference)
//
#include <hip/hip_runtime.h>
#include <math.h>

// ---------------- workspace layout (float offsets) ----------------
#define WS_G0   64      // G_s[361] (i<=j)  [zeroed by k_main corner blocks]
#define WS_G1   448     // G_t[361]
#define WS_Z    1152    // row sumexp [304]            (plain stores)
#define WS_SR   1456    // row S/Z - logZ [304]        (plain stores)
#define WS_C    1760    // corner pi partials [8]      (plain stores)
#define WS_PF   1792    // pi-finalize partials [66]   (plain stores)
#define WS_TK   1880    // completion ticket (uint)    [zeroed by k_main]
#define WS_PART 51200   // quarter partials [4][8][4224][4] f32

typedef __bf16 bf16x8 __attribute__((ext_vector_type(8)));
typedef float  f32x4  __attribute__((ext_vector_type(4)));
typedef const __attribute__((address_space(1))) unsigned int guint;
typedef       __attribute__((address_space(3))) unsigned int luint;

// ---------------- bilinear sample of t_logit row (65x65 -> 129x129) ----------------
__device__ __forceinline__ float t_resized(const float* __restrict__ Trow, int k) {
    int y = k / 129, x = k - y * 129;
    int y0 = y >> 1, x0 = x >> 1;
    int y1 = y0 + (y & 1), x1 = x0 + (x & 1);
    float fy = 0.5f * (float)(y & 1), fx = 0.5f * (float)(x & 1);
    float v00 = Trow[y0 * 65 + x0], v01 = Trow[y0 * 65 + x1];
    float v10 = Trow[y1 * 65 + x0], v11 = Trow[y1 * 65 + x1];
    float r0 = v00 + fx * (v01 - v00);
    float r1 = v10 + fx * (v11 - v10);
    return r0 + fy * (r1 - r0);
}

// ---------------- main: rowstats (0..303) + pi (304..2415) + corner px (2416..2423) --
// PROVEN round-9 pi structure (81.6 us). W now read as f32 from conv_w and
// converted to bf16 in-register (identical rounding to the old k_init path).
// vmcnt(8)/(4)/(0) waits rely only on the t-load issue order -> unaffected by
// the A-load op-count change. DO NOT raise occupancy: (256,3) is the only
// non-spilling operating point (rounds 3/5/6/10 evidence).
__launch_bounds__(256, 3)
__global__ void k_main(const float* __restrict__ s_out, const float* __restrict__ t_out,
                       const float* __restrict__ conv_w, const float* __restrict__ bias,
                       const float* __restrict__ s_logit, const float* __restrict__ t_logit,
                       float* __restrict__ ws, float* __restrict__ out) {
    __shared__ __align__(16) char lds[50176];
    const int tid = threadIdx.x;
    const int bx  = blockIdx.x;

    if (bx >= 304 && bx < 2416) {
        // ================= pi role =================
        const int idx     = bx - 304;
        const int quarter = idx & 3;
        const int bs      = idx >> 2;
        const int b       = bs / 66;
        const int strip   = bs - b * 66;
        const int px0     = strip * 64;

        const int l = tid & 63, g = tid >> 6, q = l >> 4, n = l & 15;
        const int og = quarter * 192 + g * 16;

        const float* base_t = t_out + (size_t)(b * 768 + og) * 4225;
        int off[4];
        #pragma unroll
        for (int j = 0; j < 4; j++) {
            int col = ((n * 4) + j * 16) & 63;
            off[j] = (j * 4 + q) * 4225 + px0 + col;
        }
        int colr[4];
        #pragma unroll
        for (int pt = 0; pt < 4; pt++)
            colr[pt] = (((pt * 16 + (n & 12) - q * 16) & 63)) + (n & 3);

        auto issue_t = [&](int cc) {
            char* lb = (cc == 2) ? (lds + g * 4096) : (lds + 17408 + cc * 16384 + g * 4096);
            const float* gb = base_t + (size_t)cc * 64 * 4225;
            #pragma unroll
            for (int j = 0; j < 4; j++)
                __builtin_amdgcn_global_load_lds((guint*)(gb + off[j]),
                                                 (luint*)(lb + j * 1024), 16, 0, 0);
        };

        issue_t(0);
        issue_t(1);

        __bf16* xs = (__bf16*)lds;               // 64 px x 136 c bf16

        {
            const float* Sb = s_out + b * 128 * 1089;
            #pragma unroll
            for (int ii = 0; ii < 32; ii++) {
                int id2 = tid + ii * 256;
                int c = id2 >> 6, px = id2 & 63;
                int hw = px0 + px;
                int h = hw / 65, w = hw - h * 65;
                int y0 = h >> 1, x0 = w >> 1;
                int y1 = y0 + (h & 1), x1 = x0 + (w & 1);
                float wy = 0.5f * (float)(h & 1), wx = 0.5f * (float)(w & 1);
                const float* Sc = Sb + c * 1089;
                float v00 = Sc[y0 * 33 + x0], v01 = Sc[y0 * 33 + x1];
                float v10 = Sc[y1 * 33 + x0], v11 = Sc[y1 * 33 + x1];
                float r0 = v00 + wx * (v01 - v00);
                float r1 = v10 + wx * (v11 - v10);
                xs[px * 136 + c] = (__bf16)(r0 + wy * (r1 - r0));
            }
        }
        asm volatile("s_waitcnt lgkmcnt(0)" ::: "memory");
        __builtin_amdgcn_s_barrier();
        __builtin_amdgcn_sched_barrier(0);

        bf16x8 bfrag[4][4];
        #pragma unroll
        for (int pt = 0; pt < 4; pt++)
            #pragma unroll
            for (int kf = 0; kf < 4; kf++)
                bfrag[pt][kf] = *(const bf16x8*)&xs[(pt * 16 + n) * 136 + kf * 32 + q * 8];

        bf16x8 afr[3][4];
        f32x4  bq[3];
        auto load_a = [&](int cc) {
            const float* Wr = conv_w + (size_t)(og + cc * 64 + n) * 128 + q * 8;
            #pragma unroll
            for (int kf = 0; kf < 4; kf++) {
                f32x4 w0 = *(const f32x4*)(Wr + kf * 32);
                f32x4 w1 = *(const f32x4*)(Wr + kf * 32 + 4);
                bf16x8 a;
                a[0] = (__bf16)w0[0]; a[1] = (__bf16)w0[1];
                a[2] = (__bf16)w0[2]; a[3] = (__bf16)w0[3];
                a[4] = (__bf16)w1[0]; a[5] = (__bf16)w1[1];
                a[6] = (__bf16)w1[2]; a[7] = (__bf16)w1[3];
                afr[cc][kf] = a;
            }
            bq[cc] = *(const f32x4*)&bias[og + cc * 64 + q * 4];
        };
        load_a(0);
        load_a(1);

        asm volatile("s_waitcnt lgkmcnt(0)" ::: "memory");
        __builtin_amdgcn_s_barrier();
        __builtin_amdgcn_sched_barrier(0);
        issue_t(2);

        float Zt[4], St[4], Dd[4], Zs[4];
        #pragma unroll
        for (int pt = 0; pt < 4; pt++) { Zt[pt] = 0.f; St[pt] = 0.f; Dd[pt] = 0.f; Zs[pt] = 0.f; }

        #pragma unroll
        for (int c = 0; c < 3; c++) {
            if (c == 0)      asm volatile("s_waitcnt vmcnt(8)" ::: "memory");
            else if (c == 1) asm volatile("s_waitcnt vmcnt(4)" ::: "memory");
            else             asm volatile("s_waitcnt vmcnt(0)" ::: "memory");
            if (c == 1) load_a(2);

            const float* tw = (const float*)((c == 2) ? (lds + g * 4096)
                                                      : (lds + 17408 + c * 16384 + g * 4096));
            #pragma unroll
            for (int pt = 0; pt < 4; pt++) {
                f32x4 a0 = {0.f, 0.f, 0.f, 0.f};
                #pragma unroll
                for (int kf = 0; kf < 4; kf++)
                    a0 = __builtin_amdgcn_mfma_f32_16x16x32_bf16(afr[c][kf], bfrag[pt][kf], a0, 0, 0, 0);
                #pragma unroll
                for (int r = 0; r < 4; r++) {
                    float tv  = tw[(q * 4 + r) * 64 + colr[pt]];
                    float s1v = a0[r] + bq[c][r];
                    float e   = __expf(tv);
                    Zt[pt] += e;
                    St[pt]  = fmaf(e, tv,  St[pt]);
                    Dd[pt]  = fmaf(e, s1v, Dd[pt]);
                    Zs[pt] += __expf(s1v);
                }
            }
        }

        __syncthreads();
        float* scr = (float*)lds;
        {
            int p = g * 4 + q;
            #pragma unroll
            for (int pt = 0; pt < 4; pt++) {
                f32x4 v = {Zt[pt], St[pt], Dd[pt], Zs[pt]};
                *(f32x4*)&scr[(pt * 16 + n) * 68 + p * 4] = v;
            }
        }
        __syncthreads();
        if (tid < 64) {
            float Z = 0.f, S = 0.f, D = 0.f, Z2 = 0.f;
            #pragma unroll
            for (int p = 0; p < 16; p++) {
                f32x4 v = *(const f32x4*)&scr[tid * 68 + p * 4];
                Z += v[0]; S += v[1]; D += v[2]; Z2 += v[3];
            }
            f32x4 o4 = {Z, S, D, Z2};
            *(f32x4*)&ws[WS_PART + (((size_t)quarter * 8 + b) * 4224 + px0 + tid) * 4] = o4;
        }
    } else if (bx < 304) {
        // ================= rowstats role (plain stores, no atomics) ==============
        float* red = (float*)lds;
        int row  = bx;
        int side = (row >= 152) ? 1 : 0;
        int r    = side ? row - 152 : row;
        const float* src = side ? (t_logit + r * 4225) : (s_logit + r * 16641);

        float z = 0.f, s = 0.f;
        #pragma unroll 4
        for (int k = tid; k < 16641; k += 256) {
            float v = side ? t_resized(src, k) : src[k];
            float e = __expf(v);
            z += e;
            s = fmaf(e, v, s);
        }
        for (int off = 32; off > 0; off >>= 1) { z += __shfl_down(z, off); s += __shfl_down(s, off); }
        if ((tid & 63) == 0) { red[tid >> 6] = z; red[4 + (tid >> 6)] = s; }
        __syncthreads();
        if (tid == 0) {
            float Z = red[0] + red[1] + red[2] + red[3];
            float S = red[4] + red[5] + red[6] + red[7];
            ws[WS_Z + row]  = Z;
            ws[WS_SR + row] = S / Z - logf(Z);
        }
    } else {
        // ===== corner pixel (px 4224) role + zeroing for k_mid, one block per b ==
        float* xc  = (float*)lds;          // 128
        float* red = (float*)lds + 128;    // 16
        const int b = bx - 2416;
        // zero gram accumulators [64,832) and the ticket (k_main precedes k_mid)
        if (tid < 96) ws[64 + b * 96 + tid] = 0.f;
        if (b == 0 && tid == 128) ((unsigned int*)ws)[WS_TK] = 0u;
        if (tid < 128) xc[tid] = s_out[((size_t)b * 128 + tid) * 1089 + 1088];
        __syncthreads();
        float z = 0.f, s = 0.f, d = 0.f, z2 = 0.f;
        #pragma unroll
        for (int rep = 0; rep < 3; rep++) {
            int o = tid + rep * 256;
            const float* Wr = conv_w + (size_t)o * 128;
            float s1 = bias[o];
            for (int cc = 0; cc < 128; cc++) s1 = fmaf(Wr[cc], xc[cc], s1);
            float tv = t_out[((size_t)(b * 768 + o)) * 4225 + 4224];
            float e  = __expf(tv);
            z += e; s = fmaf(e, tv, s); d = fmaf(e, s1, d); z2 += __expf(s1);
        }
        for (int off = 32; off > 0; off >>= 1) {
            z += __shfl_down(z, off); s += __shfl_down(s, off);
            d += __shfl_down(d, off); z2 += __shfl_down(z2, off);
        }
        if ((tid & 63) == 0) {
            int wv = tid >> 6;
            red[wv] = z; red[4 + wv] = s; red[8 + wv] = d; red[12 + wv] = z2;
        }
        __syncthreads();
        if (tid == 0) {
            float Z = red[0] + red[1] + red[2] + red[3];
            float S = red[4] + red[5] + red[6] + red[7];
            float D = red[8] + red[9] + red[10] + red[11];
            float Z2 = red[12] + red[13] + red[14] + red[15];
            ws[WS_C + b] = (S - D) / Z - logf(Z) + logf(Z2);   // unscaled partial
        }
    }
}

// ---------------- mid: Gram (0..527) + pi finalize (528..593) + last-block
//                  grid finalize (fence -> ticket -> winner computes both losses)
#define KT 512
#define KP 516
__global__ __launch_bounds__(512)
void k_mid(const float* __restrict__ s_logit, const float* __restrict__ t_logit,
           float* __restrict__ ws, float* __restrict__ out) {
    __shared__ __align__(16) char lds[39296];
    __shared__ int lastBlk;
    const int tid = threadIdx.x;
    const int bx  = blockIdx.x;

    if (bx < 528) {
        float* pbuf  = (float*)lds;               // [19][516]
        float* rowiz = (float*)(lds + 39216);     // [19]
        int side = (bx >= 264) ? 1 : 0;
        int rm   = side ? bx - 264 : bx;
        int b = rm / 33, kt = rm - b * 33;
        int k0 = kt * KT;

        if (tid < 19) rowiz[tid] = 1.0f / ws[WS_Z + side * 152 + b * 19 + tid];
        __syncthreads();

        const int  k   = k0 + tid;
        const bool inb = (k < 16641);

        float vb[19];
        if (side) {
            int y = k / 129, x = k - y * 129;
            int y0 = y >> 1, x0 = x >> 1;
            int y1 = y0 + (y & 1), x1 = x0 + (x & 1);
            float fy = 0.5f * (float)(y & 1), fx = 0.5f * (float)(x & 1);
            int i00 = y0 * 65 + x0, i01 = y0 * 65 + x1;
            int i10 = y1 * 65 + x0, i11 = y1 * 65 + x1;
            const float* Tb = t_logit + (size_t)b * 19 * 4225;
            #pragma unroll
            for (int i = 0; i < 19; i++) {
                if (inb) {
                    const float* Trow = Tb + i * 4225;
                    float v00 = Trow[i00], v01 = Trow[i01];
                    float v10 = Trow[i10], v11 = Trow[i11];
                    float r0 = v00 + fx * (v01 - v00);
                    float r1 = v10 + fx * (v11 - v10);
                    vb[i] = r0 + fy * (r1 - r0);
                } else vb[i] = 0.f;
            }
        } else {
            const float* Sb = s_logit + (size_t)b * 19 * 16641;
            #pragma unroll
            for (int i = 0; i < 19; i++)
                vb[i] = inb ? Sb[(size_t)i * 16641 + k] : 0.f;
        }
        #pragma unroll
        for (int i = 0; i < 19; i++)
            pbuf[i * KP + tid] = inb ? (__expf(vb[i]) * rowiz[i]) : 0.f;
        __syncthreads();

        if (tid < 380) {
            int pr = tid >> 1, h = tid & 1;
            int t = pr, i = 0;
            while (t >= 19 - i) { t -= 19 - i; i++; }
            int j = i + t;
            const float* pi_ = &pbuf[i * KP + h * 256];
            const float* pj_ = &pbuf[j * KP + h * 256];
            float g0 = 0.f, g1 = 0.f, g2 = 0.f, g3 = 0.f;
            #pragma unroll 2
            for (int kl = 0; kl < 256; kl += 16) {
                float4 a0 = *(const float4*)&pi_[kl];      float4 c0 = *(const float4*)&pj_[kl];
                float4 a1 = *(const float4*)&pi_[kl + 4];  float4 c1 = *(const float4*)&pj_[kl + 4];
                float4 a2 = *(const float4*)&pi_[kl + 8];  float4 c2 = *(const float4*)&pj_[kl + 8];
                float4 a3 = *(const float4*)&pi_[kl + 12]; float4 c3 = *(const float4*)&pj_[kl + 12];
                g0 = fmaf(a0.x, c0.x, g0); g0 = fmaf(a0.y, c0.y, g0);
                g0 = fmaf(a0.z, c0.z, g0); g0 = fmaf(a0.w, c0.w, g0);
                g1 = fmaf(a1.x, c1.x, g1); g1 = fmaf(a1.y, c1.y, g1);
                g1 = fmaf(a1.z, c1.z, g1); g1 = fmaf(a1.w, c1.w, g1);
                g2 = fmaf(a2.x, c2.x, g2); g2 = fmaf(a2.y, c2.y, g2);
                g2 = fmaf(a2.z, c2.z, g2); g2 = fmaf(a2.w, c2.w, g2);
                g3 = fmaf(a3.x, c3.x, g3); g3 = fmaf(a3.y, c3.y, g3);
                g3 = fmaf(a3.z, c3.z, g3); g3 = fmaf(a3.w, c3.w, g3);
            }
            float g = (g0 + g1) + (g2 + g3);
            g += __shfl_xor(g, 1);
            if (h == 0)
                atomicAdd(&ws[(side ? WS_G1 : WS_G0) + i * 19 + j], g);
        }
    } else {
        // pi finalize: 66 blocks x 512 threads = 33792 = 8 b x 4224 px
        float* red = (float*)lds;
        int gp = (bx - 528) * 512 + tid;
        int b  = gp / 4224;
        int tp = gp - b * 4224;
        float Z = 0.f, S = 0.f, D = 0.f, Z2 = 0.f;
        #pragma unroll
        for (int qq = 0; qq < 4; qq++) {
            f32x4 v = *(const f32x4*)&ws[WS_PART + (((size_t)qq * 8 + b) * 4224 + tp) * 4];
            Z += v[0]; S += v[1]; D += v[2]; Z2 += v[3];
        }
        float contrib = (S - D) / Z - logf(Z) + logf(Z2);
        for (int off = 32; off > 0; off >>= 1) contrib += __shfl_down(contrib, off);
        if ((tid & 63) == 0) red[tid >> 6] = contrib;
        __syncthreads();
        if (tid == 0) {
            float tot = 0.f;
            #pragma unroll
            for (int w = 0; w < 8; w++) tot += red[w];
            ws[WS_PF + (bx - 528)] = tot;         // unscaled partial, plain store
        }
    }

    // ===== grid-completion ticket; last block computes both losses =====
    __threadfence();
    if (tid == 0)
        lastBlk = (atomicAdd(&((unsigned int*)ws)[WS_TK], 1u) == 593u);
    __syncthreads();
    if (!lastBlk) return;
    __threadfence();

    float* Ms  = (float*)lds;            // 361
    float* Mt  = Ms + 361;               // 361
    float* El  = Mt + 361;               // 38
    float* ns  = El + 38;                // 19
    float* nt  = ns + 19;                // 19
    float* red = nt + 19;                // 16

    if (tid < 38) {
        int sd = (tid >= 19) ? 1 : 0, i = tid - sd * 19;
        float e = 0.f;
        #pragma unroll
        for (int b = 0; b < 8; b++) e += ws[WS_SR + sd * 152 + b * 19 + i];
        El[tid] = e;
    }
    {
        float v = 0.f;
        if (tid < 66) v = ws[WS_PF + tid];
        else if (tid < 74) v = ws[WS_C + tid - 66];
        if (tid < 128) {
            #pragma unroll
            for (int o = 32; o > 0; o >>= 1) v += __shfl_down(v, o);
            if ((tid & 63) == 0) red[8 + (tid >> 6)] = v;
        }
    }
    __syncthreads();
    if (tid == 0) out[0] = (red[8] + red[9]) * (1.0f / 25958400.0f);
    if (tid < 361) {
        int i = tid / 19, j = tid - i * 19;
        int lo = min(i, j), hi = max(i, j);
        Ms[tid] = (El[hi]      - ws[WS_G0 + lo * 19 + hi]) * 0.125f;
        Mt[tid] = (El[19 + hi] - ws[WS_G1 + lo * 19 + hi]) * 0.125f;
    }
    __syncthreads();
    if (tid < 19) {
        float as = 0.f, at = 0.f;
        for (int j = 0; j < 19; j++) {
            as = fmaf(Ms[tid * 19 + j], Ms[tid * 19 + j], as);
            at = fmaf(Mt[tid * 19 + j], Mt[tid * 19 + j], at);
        }
        ns[tid] = fmaxf(sqrtf(as), 1e-12f);
        nt[tid] = fmaxf(sqrtf(at), 1e-12f);
    }
    __syncthreads();
    float d = 0.f;
    if (tid < 361) {
        int i = tid / 19;
        float v = Ms[tid] / ns[i] - Mt[tid] / nt[i];
        d = v * v;
    }
    #pragma unroll
    for (int o = 32; o > 0; o >>= 1) d += __shfl_down(d, o);
    if ((tid & 63) == 0) red[tid >> 6] = d;
    __syncthreads();
    if (tid == 0) {
        float tot = 0.f;
        #pragma unroll
        for (int w = 0; w < 8; w++) tot += red[w];
        out[1] = tot;
    }
}

extern "C" void kernel_launch(void* const* d_in, const int* in_sizes, int n_in,
                              void* d_out, int out_size, void* d_ws, size_t ws_size,
                              hipStream_t stream) {
    const float* s_out   = (const float*)d_in[0];
    const float* t_out   = (const float*)d_in[1];
    const float* t_logit = (const float*)d_in[2];
    const float* s_logit = (const float*)d_in[3];
    const float* conv_w  = (const float*)d_in[4];
    const float* conv_b  = (const float*)d_in[5];
    float* out = (float*)d_out;
    float* ws  = (float*)d_ws;

    k_main<<<dim3(2424), dim3(256), 0, stream>>>(s_out, t_out, conv_w, conv_b,
                                                 s_logit, t_logit, ws, out);
    k_mid<<<dim3(594), dim3(512), 0, stream>>>(s_logit, t_logit, ws, out);
}

// Round 13
// 294.427 us; speedup vs baseline: 1.1161x; 1.1161x over previous
//
#include <hip/hip_runtime.h>
#include <math.h>

// ---------------- workspace layout (float offsets) ----------------
#define WS_E0   0       // E_s[19]
#define WS_E1   19      // E_t[19]
#define WS_G0   64      // G_s[361] (i<=j)
#define WS_G1   448     // G_t[361]
#define WS_Z    1152    // row sumexp [304]
#define WS_TK   1900    // completion ticket (uint, zeroed by k_init each iter)
#define WS_WBF  2048    // conv_w as bf16 [768*128] -> 49152 float slots
#define WS_PART 51200   // quarter partials [4][8][4224][4] f32 = 540672 floats

typedef __bf16 bf16x8 __attribute__((ext_vector_type(8)));
typedef float  f32x4  __attribute__((ext_vector_type(4)));
typedef const __attribute__((address_space(1))) unsigned int guint;
typedef       __attribute__((address_space(3))) unsigned int luint;

// ---------------- init: zero accumulators + convert W to bf16 ----------------
__global__ void k_init(const float* __restrict__ conv_w, float* __restrict__ ws,
                       float* __restrict__ out) {
    const int bx = blockIdx.x, tid = threadIdx.x;
    if (bx < 96) {
        __bf16* Wb = (__bf16*)(ws + WS_WBF);
        #pragma unroll
        for (int j = 0; j < 4; j++) {
            int idx = bx * 1024 + j * 256 + tid;
            Wb[idx] = (__bf16)conv_w[idx];
        }
    } else {
        for (int k = tid; k < 2048; k += 256) ws[k] = 0.f;   // includes WS_TK
        if (tid < 2) out[tid] = 0.f;
    }
}

// ---------------- bilinear sample of t_logit row (65x65 -> 129x129) ----------------
__device__ __forceinline__ float t_resized(const float* __restrict__ Trow, int k) {
    int y = k / 129, x = k - y * 129;
    int y0 = y >> 1, x0 = x >> 1;
    int y1 = y0 + (y & 1), x1 = x0 + (x & 1);
    float fy = 0.5f * (float)(y & 1), fx = 0.5f * (float)(x & 1);
    float v00 = Trow[y0 * 65 + x0], v01 = Trow[y0 * 65 + x1];
    float v10 = Trow[y1 * 65 + x0], v11 = Trow[y1 * 65 + x1];
    float r0 = v00 + fx * (v01 - v00);
    float r1 = v10 + fx * (v11 - v10);
    return r0 + fy * (r1 - r0);
}

// ---------------- main: rowstats (0..303) + pi (304..2415) + corner px (2416..2423) --
// PROVEN round-9/11 build (81.6 us). W pre-converted to bf16 by k_init (inline
// conversion spills -- round-12 evidence). (256,3) is the only non-spilling
// operating point (rounds 3/5/6/10/12 evidence). Do not touch.
__launch_bounds__(256, 3)
__global__ void k_main(const float* __restrict__ s_out, const float* __restrict__ t_out,
                       const float* __restrict__ conv_w, const float* __restrict__ bias,
                       const float* __restrict__ s_logit, const float* __restrict__ t_logit,
                       float* __restrict__ ws, float* __restrict__ out) {
    __shared__ __align__(16) char lds[50176];
    const int tid = threadIdx.x;
    const int bx  = blockIdx.x;

    if (bx >= 304 && bx < 2416) {
        // ================= pi role =================
        const int idx     = bx - 304;
        const int quarter = idx & 3;
        const int bs      = idx >> 2;
        const int b       = bs / 66;
        const int strip   = bs - b * 66;
        const int px0     = strip * 64;

        const int l = tid & 63, g = tid >> 6, q = l >> 4, n = l & 15;
        const int og = quarter * 192 + g * 16;

        const float* base_t = t_out + (size_t)(b * 768 + og) * 4225;
        int off[4];
        #pragma unroll
        for (int j = 0; j < 4; j++) {
            int col = ((n * 4) + j * 16) & 63;
            off[j] = (j * 4 + q) * 4225 + px0 + col;
        }
        int colr[4];
        #pragma unroll
        for (int pt = 0; pt < 4; pt++)
            colr[pt] = (((pt * 16 + (n & 12) - q * 16) & 63)) + (n & 3);

        auto issue_t = [&](int cc) {
            char* lb = (cc == 2) ? (lds + g * 4096) : (lds + 17408 + cc * 16384 + g * 4096);
            const float* gb = base_t + (size_t)cc * 64 * 4225;
            #pragma unroll
            for (int j = 0; j < 4; j++)
                __builtin_amdgcn_global_load_lds((guint*)(gb + off[j]),
                                                 (luint*)(lb + j * 1024), 16, 0, 0);
        };

        issue_t(0);
        issue_t(1);

        __bf16* xs = (__bf16*)lds;               // 64 px x 136 c bf16

        {
            const float* Sb = s_out + b * 128 * 1089;
            #pragma unroll
            for (int ii = 0; ii < 32; ii++) {
                int id2 = tid + ii * 256;
                int c = id2 >> 6, px = id2 & 63;
                int hw = px0 + px;
                int h = hw / 65, w = hw - h * 65;
                int y0 = h >> 1, x0 = w >> 1;
                int y1 = y0 + (h & 1), x1 = x0 + (w & 1);
                float wy = 0.5f * (float)(h & 1), wx = 0.5f * (float)(w & 1);
                const float* Sc = Sb + c * 1089;
                float v00 = Sc[y0 * 33 + x0], v01 = Sc[y0 * 33 + x1];
                float v10 = Sc[y1 * 33 + x0], v11 = Sc[y1 * 33 + x1];
                float r0 = v00 + wx * (v01 - v00);
                float r1 = v10 + wx * (v11 - v10);
                xs[px * 136 + c] = (__bf16)(r0 + wy * (r1 - r0));
            }
        }
        asm volatile("s_waitcnt lgkmcnt(0)" ::: "memory");
        __builtin_amdgcn_s_barrier();
        __builtin_amdgcn_sched_barrier(0);

        bf16x8 bfrag[4][4];
        #pragma unroll
        for (int pt = 0; pt < 4; pt++)
            #pragma unroll
            for (int kf = 0; kf < 4; kf++)
                bfrag[pt][kf] = *(const bf16x8*)&xs[(pt * 16 + n) * 136 + kf * 32 + q * 8];

        const __bf16* Wbf = (const __bf16*)(ws + WS_WBF);
        bf16x8 afr[3][4];
        f32x4  bq[3];
        auto load_a = [&](int cc) {
            const __bf16* Wr = Wbf + (size_t)(og + cc * 64 + n) * 128 + q * 8;
            #pragma unroll
            for (int kf = 0; kf < 4; kf++) afr[cc][kf] = *(const bf16x8*)(Wr + kf * 32);
            bq[cc] = *(const f32x4*)&bias[og + cc * 64 + q * 4];
        };
        load_a(0);
        load_a(1);

        asm volatile("s_waitcnt lgkmcnt(0)" ::: "memory");
        __builtin_amdgcn_s_barrier();
        __builtin_amdgcn_sched_barrier(0);
        issue_t(2);

        float Zt[4], St[4], Dd[4], Zs[4];
        #pragma unroll
        for (int pt = 0; pt < 4; pt++) { Zt[pt] = 0.f; St[pt] = 0.f; Dd[pt] = 0.f; Zs[pt] = 0.f; }

        #pragma unroll
        for (int c = 0; c < 3; c++) {
            if (c == 0)      asm volatile("s_waitcnt vmcnt(8)" ::: "memory");
            else if (c == 1) asm volatile("s_waitcnt vmcnt(4)" ::: "memory");
            else             asm volatile("s_waitcnt vmcnt(0)" ::: "memory");
            if (c == 1) load_a(2);

            const float* tw = (const float*)((c == 2) ? (lds + g * 4096)
                                                      : (lds + 17408 + c * 16384 + g * 4096));
            #pragma unroll
            for (int pt = 0; pt < 4; pt++) {
                f32x4 a0 = {0.f, 0.f, 0.f, 0.f};
                #pragma unroll
                for (int kf = 0; kf < 4; kf++)
                    a0 = __builtin_amdgcn_mfma_f32_16x16x32_bf16(afr[c][kf], bfrag[pt][kf], a0, 0, 0, 0);
                #pragma unroll
                for (int r = 0; r < 4; r++) {
                    float tv  = tw[(q * 4 + r) * 64 + colr[pt]];
                    float s1v = a0[r] + bq[c][r];
                    float e   = __expf(tv);
                    Zt[pt] += e;
                    St[pt]  = fmaf(e, tv,  St[pt]);
                    Dd[pt]  = fmaf(e, s1v, Dd[pt]);
                    Zs[pt] += __expf(s1v);
                }
            }
        }

        __syncthreads();
        float* scr = (float*)lds;
        {
            int p = g * 4 + q;
            #pragma unroll
            for (int pt = 0; pt < 4; pt++) {
                f32x4 v = {Zt[pt], St[pt], Dd[pt], Zs[pt]};
                *(f32x4*)&scr[(pt * 16 + n) * 68 + p * 4] = v;
            }
        }
        __syncthreads();
        if (tid < 64) {
            float Z = 0.f, S = 0.f, D = 0.f, Z2 = 0.f;
            #pragma unroll
            for (int p = 0; p < 16; p++) {
                f32x4 v = *(const f32x4*)&scr[tid * 68 + p * 4];
                Z += v[0]; S += v[1]; D += v[2]; Z2 += v[3];
            }
            f32x4 o4 = {Z, S, D, Z2};
            *(f32x4*)&ws[WS_PART + (((size_t)quarter * 8 + b) * 4224 + px0 + tid) * 4] = o4;
        }
    } else if (bx < 304) {
        // ================= rowstats role =================
        float* red = (float*)lds;
        int row  = bx;
        int side = (row >= 152) ? 1 : 0;
        int r    = side ? row - 152 : row;
        const float* src = side ? (t_logit + r * 4225) : (s_logit + r * 16641);

        float z = 0.f, s = 0.f;
        #pragma unroll 4
        for (int k = tid; k < 16641; k += 256) {
            float v = side ? t_resized(src, k) : src[k];
            float e = __expf(v);
            z += e;
            s = fmaf(e, v, s);
        }
        for (int off = 32; off > 0; off >>= 1) { z += __shfl_down(z, off); s += __shfl_down(s, off); }
        if ((tid & 63) == 0) { red[tid >> 6] = z; red[4 + (tid >> 6)] = s; }
        __syncthreads();
        if (tid == 0) {
            float Z = red[0] + red[1] + red[2] + red[3];
            float S = red[4] + red[5] + red[6] + red[7];
            ws[WS_Z + row] = Z;
            atomicAdd(&ws[(side ? WS_E1 : WS_E0) + (r % 19)], S / Z - logf(Z));
        }
    } else {
        // ================= corner pixel (px 4224) role, one block per b ==========
        float* xc  = (float*)lds;          // 128
        float* red = (float*)lds + 128;    // 16
        const int b = bx - 2416;
        if (tid < 128) xc[tid] = s_out[((size_t)b * 128 + tid) * 1089 + 1088];
        __syncthreads();
        float z = 0.f, s = 0.f, d = 0.f, z2 = 0.f;
        #pragma unroll
        for (int rep = 0; rep < 3; rep++) {
            int o = tid + rep * 256;
            const float* Wr = conv_w + (size_t)o * 128;
            float s1 = bias[o];
            for (int cc = 0; cc < 128; cc++) s1 = fmaf(Wr[cc], xc[cc], s1);
            float tv = t_out[((size_t)(b * 768 + o)) * 4225 + 4224];
            float e  = __expf(tv);
            z += e; s = fmaf(e, tv, s); d = fmaf(e, s1, d); z2 += __expf(s1);
        }
        for (int off = 32; off > 0; off >>= 1) {
            z += __shfl_down(z, off); s += __shfl_down(s, off);
            d += __shfl_down(d, off); z2 += __shfl_down(z2, off);
        }
        if ((tid & 63) == 0) {
            int wv = tid >> 6;
            red[wv] = z; red[4 + wv] = s; red[8 + wv] = d; red[12 + wv] = z2;
        }
        __syncthreads();
        if (tid == 0) {
            float Z = red[0] + red[1] + red[2] + red[3];
            float S = red[4] + red[5] + red[6] + red[7];
            float D = red[8] + red[9] + red[10] + red[11];
            float Z2 = red[12] + red[13] + red[14] + red[15];
            float contrib = (S - D) / Z - logf(Z) + logf(Z2);
            atomicAdd(out, contrib * (1.0f / 25958400.0f));
        }
    }
}

// ---------------- mid: Gram (0..527) + pi finalize (528..593) + ticket winner
//                  runs the old k_final body (one fewer dispatch) ----------------
#define KT 512
#define KP 516
__global__ __launch_bounds__(512)
void k_mid(const float* __restrict__ s_logit, const float* __restrict__ t_logit,
           float* __restrict__ ws, float* __restrict__ out) {
    __shared__ __align__(16) char lds[39296];
    __shared__ int lastBlk;
    const int tid = threadIdx.x;
    const int bx  = blockIdx.x;

    if (bx < 528) {
        float* pbuf  = (float*)lds;               // [19][516]
        float* rowiz = (float*)(lds + 39216);     // [19]
        int side = (bx >= 264) ? 1 : 0;
        int rm   = side ? bx - 264 : bx;
        int b = rm / 33, kt = rm - b * 33;
        int k0 = kt * KT;

        if (tid < 19) rowiz[tid] = 1.0f / ws[WS_Z + side * 152 + b * 19 + tid];
        __syncthreads();

        const int  k   = k0 + tid;
        const bool inb = (k < 16641);

        float vb[19];
        if (side) {
            int y = k / 129, x = k - y * 129;
            int y0 = y >> 1, x0 = x >> 1;
            int y1 = y0 + (y & 1), x1 = x0 + (x & 1);
            float fy = 0.5f * (float)(y & 1), fx = 0.5f * (float)(x & 1);
            int i00 = y0 * 65 + x0, i01 = y0 * 65 + x1;
            int i10 = y1 * 65 + x0, i11 = y1 * 65 + x1;
            const float* Tb = t_logit + (size_t)b * 19 * 4225;
            #pragma unroll
            for (int i = 0; i < 19; i++) {
                if (inb) {
                    const float* Trow = Tb + i * 4225;
                    float v00 = Trow[i00], v01 = Trow[i01];
                    float v10 = Trow[i10], v11 = Trow[i11];
                    float r0 = v00 + fx * (v01 - v00);
                    float r1 = v10 + fx * (v11 - v10);
                    vb[i] = r0 + fy * (r1 - r0);
                } else vb[i] = 0.f;
            }
        } else {
            const float* Sb = s_logit + (size_t)b * 19 * 16641;
            #pragma unroll
            for (int i = 0; i < 19; i++)
                vb[i] = inb ? Sb[(size_t)i * 16641 + k] : 0.f;
        }
        #pragma unroll
        for (int i = 0; i < 19; i++)
            pbuf[i * KP + tid] = inb ? (__expf(vb[i]) * rowiz[i]) : 0.f;
        __syncthreads();

        if (tid < 380) {
            int pr = tid >> 1, h = tid & 1;
            int t = pr, i = 0;
            while (t >= 19 - i) { t -= 19 - i; i++; }
            int j = i + t;
            const float* pi_ = &pbuf[i * KP + h * 256];
            const float* pj_ = &pbuf[j * KP + h * 256];
            float g0 = 0.f, g1 = 0.f, g2 = 0.f, g3 = 0.f;
            #pragma unroll 2
            for (int kl = 0; kl < 256; kl += 16) {
                float4 a0 = *(const float4*)&pi_[kl];      float4 c0 = *(const float4*)&pj_[kl];
                float4 a1 = *(const float4*)&pi_[kl + 4];  float4 c1 = *(const float4*)&pj_[kl + 4];
                float4 a2 = *(const float4*)&pi_[kl + 8];  float4 c2 = *(const float4*)&pj_[kl + 8];
                float4 a3 = *(const float4*)&pi_[kl + 12]; float4 c3 = *(const float4*)&pj_[kl + 12];
                g0 = fmaf(a0.x, c0.x, g0); g0 = fmaf(a0.y, c0.y, g0);
                g0 = fmaf(a0.z, c0.z, g0); g0 = fmaf(a0.w, c0.w, g0);
                g1 = fmaf(a1.x, c1.x, g1); g1 = fmaf(a1.y, c1.y, g1);
                g1 = fmaf(a1.z, c1.z, g1); g1 = fmaf(a1.w, c1.w, g1);
                g2 = fmaf(a2.x, c2.x, g2); g2 = fmaf(a2.y, c2.y, g2);
                g2 = fmaf(a2.z, c2.z, g2); g2 = fmaf(a2.w, c2.w, g2);
                g3 = fmaf(a3.x, c3.x, g3); g3 = fmaf(a3.y, c3.y, g3);
                g3 = fmaf(a3.z, c3.z, g3); g3 = fmaf(a3.w, c3.w, g3);
            }
            float g = (g0 + g1) + (g2 + g3);
            g += __shfl_xor(g, 1);
            if (h == 0)
                atomicAdd(&ws[(side ? WS_G1 : WS_G0) + i * 19 + j], g);
        }
    } else {
        // pi finalize: 66 blocks x 512 threads = 33792 = 8 b x 4224 px
        float* red = (float*)lds;
        int gp = (bx - 528) * 512 + tid;
        int b  = gp / 4224;
        int tp = gp - b * 4224;
        float Z = 0.f, S = 0.f, D = 0.f, Z2 = 0.f;
        #pragma unroll
        for (int qq = 0; qq < 4; qq++) {
            f32x4 v = *(const f32x4*)&ws[WS_PART + (((size_t)qq * 8 + b) * 4224 + tp) * 4];
            Z += v[0]; S += v[1]; D += v[2]; Z2 += v[3];
        }
        float contrib = (S - D) / Z - logf(Z) + logf(Z2);
        for (int off = 32; off > 0; off >>= 1) contrib += __shfl_down(contrib, off);
        if ((tid & 63) == 0) red[tid >> 6] = contrib;
        __syncthreads();
        if (tid == 0) {
            float tot = 0.f;
            #pragma unroll
            for (int w = 0; w < 8; w++) tot += red[w];
            atomicAdd(out, tot * (1.0f / 25958400.0f));
        }
    }

    // ===== grid-completion ticket; winner runs the old k_final =====
    __threadfence();
    __syncthreads();
    if (tid == 0)
        lastBlk = (atomicAdd(&((unsigned int*)ws)[WS_TK], 1u) == 593u) ? 1 : 0;
    __syncthreads();
    if (!lastBlk) return;
    __threadfence();

    float* Ms  = (float*)lds;            // 361
    float* Mt  = Ms + 361;               // 361
    float* ns  = Mt + 361;               // 19
    float* nt  = ns + 19;                // 19
    float* red = nt + 19;                // 8
    __syncthreads();

    if (tid < 361) {
        int i = tid / 19, j = tid - i * 19;
        int lo = min(i, j), hi = max(i, j);
        Ms[tid] = (ws[WS_E0 + hi] - ws[WS_G0 + lo * 19 + hi]) * 0.125f;
        Mt[tid] = (ws[WS_E1 + hi] - ws[WS_G1 + lo * 19 + hi]) * 0.125f;
    }
    __syncthreads();
    if (tid < 19) {
        float as = 0.f, at = 0.f;
        for (int j = 0; j < 19; j++) {
            as = fmaf(Ms[tid * 19 + j], Ms[tid * 19 + j], as);
            at = fmaf(Mt[tid * 19 + j], Mt[tid * 19 + j], at);
        }
        ns[tid] = fmaxf(sqrtf(as), 1e-12f);
        nt[tid] = fmaxf(sqrtf(at), 1e-12f);
    }
    __syncthreads();
    float d = 0.f;
    if (tid < 361) {
        int i = tid / 19;
        float v = Ms[tid] / ns[i] - Mt[tid] / nt[i];
        d = v * v;
    }
    #pragma unroll
    for (int o = 32; o > 0; o >>= 1) d += __shfl_down(d, o);
    if ((tid & 63) == 0) red[tid >> 6] = d;
    __syncthreads();
    if (tid == 0) {
        float tot = 0.f;
        #pragma unroll
        for (int w = 0; w < 8; w++) tot += red[w];
        out[1] = tot;
    }
}

extern "C" void kernel_launch(void* const* d_in, const int* in_sizes, int n_in,
                              void* d_out, int out_size, void* d_ws, size_t ws_size,
                              hipStream_t stream) {
    const float* s_out   = (const float*)d_in[0];
    const float* t_out   = (const float*)d_in[1];
    const float* t_logit = (const float*)d_in[2];
    const float* s_logit = (const float*)d_in[3];
    const float* conv_w  = (const float*)d_in[4];
    const float* conv_b  = (const float*)d_in[5];
    float* out = (float*)d_out;
    float* ws  = (float*)d_ws;

    k_init<<<dim3(97), dim3(256), 0, stream>>>(conv_w, ws, out);
    k_main<<<dim3(2424), dim3(256), 0, stream>>>(s_out, t_out, conv_w, conv_b,
                                                 s_logit, t_logit, ws, out);
    k_mid<<<dim3(594), dim3(512), 0, stream>>>(s_logit, t_logit, ws, out);
}

// Round 14
// 234.183 us; speedup vs baseline: 1.4032x; 1.2573x over previous
//
#include <hip/hip_runtime.h>
#include <math.h>

// ---------------- workspace layout (float offsets) ----------------
#define WS_E0   0       // E_s[19]
#define WS_E1   19      // E_t[19]
#define WS_G0   64      // G_s[361] (i<=j)
#define WS_G1   448     // G_t[361]
#define WS_Z    1152    // row sumexp [304]
#define WS_WBF  2048    // conv_w as bf16 [768*128] -> 49152 float slots
#define WS_PART 51200   // quarter partials [4][8][4224][4] f32 = 540672 floats

typedef __bf16 bf16x8 __attribute__((ext_vector_type(8)));
typedef float  f32x4  __attribute__((ext_vector_type(4)));
typedef const __attribute__((address_space(1))) unsigned int guint;
typedef       __attribute__((address_space(3))) unsigned int luint;

// ---------------- init: zero accumulators + convert W to bf16 ----------------
__global__ void k_init(const float* __restrict__ conv_w, float* __restrict__ ws,
                       float* __restrict__ out) {
    const int bx = blockIdx.x, tid = threadIdx.x;
    if (bx < 96) {
        __bf16* Wb = (__bf16*)(ws + WS_WBF);
        #pragma unroll
        for (int j = 0; j < 4; j++) {
            int idx = bx * 1024 + j * 256 + tid;
            Wb[idx] = (__bf16)conv_w[idx];
        }
    } else {
        for (int k = tid; k < 2048; k += 256) ws[k] = 0.f;
        if (tid < 2) out[tid] = 0.f;
    }
}

// ---------------- bilinear sample of t_logit row (65x65 -> 129x129) ----------------
__device__ __forceinline__ float t_resized(const float* __restrict__ Trow, int k) {
    int y = k / 129, x = k - y * 129;
    int y0 = y >> 1, x0 = x >> 1;
    int y1 = y0 + (y & 1), x1 = x0 + (x & 1);
    float fy = 0.5f * (float)(y & 1), fx = 0.5f * (float)(x & 1);
    float v00 = Trow[y0 * 65 + x0], v01 = Trow[y0 * 65 + x1];
    float v10 = Trow[y1 * 65 + x0], v11 = Trow[y1 * 65 + x1];
    float r0 = v00 + fx * (v01 - v00);
    float r1 = v10 + fx * (v11 - v10);
    return r0 + fy * (r1 - r0);
}

// ---------------- main: rowstats (0..303) + pi (304..2415) + corner px (2416..2423) --
// PROVEN round-9 build (81.6 us): pi block = (b, strip of 64 px, ch-quarter of 192).
// t_out: 3 chunks, ALL issued before first use; raw s_barrier + lgkmcnt keeps
// prefetch in flight; waits vmcnt(8)/(4)/(0). DO NOT raise occupancy: (256,3)
// is the only non-spilling operating point (rounds 3/5/6/10/12 evidence).
__launch_bounds__(256, 3)
__global__ void k_main(const float* __restrict__ s_out, const float* __restrict__ t_out,
                       const float* __restrict__ conv_w, const float* __restrict__ bias,
                       const float* __restrict__ s_logit, const float* __restrict__ t_logit,
                       float* __restrict__ ws, float* __restrict__ out) {
    __shared__ __align__(16) char lds[50176];
    const int tid = threadIdx.x;
    const int bx  = blockIdx.x;

    if (bx >= 304 && bx < 2416) {
        // ================= pi role =================
        const int idx     = bx - 304;
        const int quarter = idx & 3;
        const int bs      = idx >> 2;
        const int b       = bs / 66;
        const int strip   = bs - b * 66;
        const int px0     = strip * 64;

        const int l = tid & 63, g = tid >> 6, q = l >> 4, n = l & 15;
        const int og = quarter * 192 + g * 16;

        const float* base_t = t_out + (size_t)(b * 768 + og) * 4225;
        int off[4];
        #pragma unroll
        for (int j = 0; j < 4; j++) {
            int col = ((n * 4) + j * 16) & 63;
            off[j] = (j * 4 + q) * 4225 + px0 + col;
        }
        int colr[4];
        #pragma unroll
        for (int pt = 0; pt < 4; pt++)
            colr[pt] = (((pt * 16 + (n & 12) - q * 16) & 63)) + (n & 3);

        auto issue_t = [&](int cc) {
            char* lb = (cc == 2) ? (lds + g * 4096) : (lds + 17408 + cc * 16384 + g * 4096);
            const float* gb = base_t + (size_t)cc * 64 * 4225;
            #pragma unroll
            for (int j = 0; j < 4; j++)
                __builtin_amdgcn_global_load_lds((guint*)(gb + off[j]),
                                                 (luint*)(lb + j * 1024), 16, 0, 0);
        };

        issue_t(0);
        issue_t(1);

        __bf16* xs = (__bf16*)lds;               // 64 px x 136 c bf16

        {
            const float* Sb = s_out + b * 128 * 1089;
            #pragma unroll
            for (int ii = 0; ii < 32; ii++) {
                int id2 = tid + ii * 256;
                int c = id2 >> 6, px = id2 & 63;
                int hw = px0 + px;
                int h = hw / 65, w = hw - h * 65;
                int y0 = h >> 1, x0 = w >> 1;
                int y1 = y0 + (h & 1), x1 = x0 + (w & 1);
                float wy = 0.5f * (float)(h & 1), wx = 0.5f * (float)(w & 1);
                const float* Sc = Sb + c * 1089;
                float v00 = Sc[y0 * 33 + x0], v01 = Sc[y0 * 33 + x1];
                float v10 = Sc[y1 * 33 + x0], v11 = Sc[y1 * 33 + x1];
                float r0 = v00 + wx * (v01 - v00);
                float r1 = v10 + wx * (v11 - v10);
                xs[px * 136 + c] = (__bf16)(r0 + wy * (r1 - r0));
            }
        }
        asm volatile("s_waitcnt lgkmcnt(0)" ::: "memory");
        __builtin_amdgcn_s_barrier();
        __builtin_amdgcn_sched_barrier(0);

        bf16x8 bfrag[4][4];
        #pragma unroll
        for (int pt = 0; pt < 4; pt++)
            #pragma unroll
            for (int kf = 0; kf < 4; kf++)
                bfrag[pt][kf] = *(const bf16x8*)&xs[(pt * 16 + n) * 136 + kf * 32 + q * 8];

        const __bf16* Wbf = (const __bf16*)(ws + WS_WBF);
        bf16x8 afr[3][4];
        f32x4  bq[3];
        auto load_a = [&](int cc) {
            const __bf16* Wr = Wbf + (size_t)(og + cc * 64 + n) * 128 + q * 8;
            #pragma unroll
            for (int kf = 0; kf < 4; kf++) afr[cc][kf] = *(const bf16x8*)(Wr + kf * 32);
            bq[cc] = *(const f32x4*)&bias[og + cc * 64 + q * 4];
        };
        load_a(0);
        load_a(1);

        asm volatile("s_waitcnt lgkmcnt(0)" ::: "memory");
        __builtin_amdgcn_s_barrier();
        __builtin_amdgcn_sched_barrier(0);
        issue_t(2);

        float Zt[4], St[4], Dd[4], Zs[4];
        #pragma unroll
        for (int pt = 0; pt < 4; pt++) { Zt[pt] = 0.f; St[pt] = 0.f; Dd[pt] = 0.f; Zs[pt] = 0.f; }

        #pragma unroll
        for (int c = 0; c < 3; c++) {
            if (c == 0)      asm volatile("s_waitcnt vmcnt(8)" ::: "memory");
            else if (c == 1) asm volatile("s_waitcnt vmcnt(4)" ::: "memory");
            else             asm volatile("s_waitcnt vmcnt(0)" ::: "memory");
            if (c == 1) load_a(2);

            const float* tw = (const float*)((c == 2) ? (lds + g * 4096)
                                                      : (lds + 17408 + c * 16384 + g * 4096));
            #pragma unroll
            for (int pt = 0; pt < 4; pt++) {
                f32x4 a0 = {0.f, 0.f, 0.f, 0.f};
                #pragma unroll
                for (int kf = 0; kf < 4; kf++)
                    a0 = __builtin_amdgcn_mfma_f32_16x16x32_bf16(afr[c][kf], bfrag[pt][kf], a0, 0, 0, 0);
                #pragma unroll
                for (int r = 0; r < 4; r++) {
                    float tv  = tw[(q * 4 + r) * 64 + colr[pt]];
                    float s1v = a0[r] + bq[c][r];
                    float e   = __expf(tv);
                    Zt[pt] += e;
                    St[pt]  = fmaf(e, tv,  St[pt]);
                    Dd[pt]  = fmaf(e, s1v, Dd[pt]);
                    Zs[pt] += __expf(s1v);
                }
            }
        }

        __syncthreads();
        float* scr = (float*)lds;
        {
            int p = g * 4 + q;
            #pragma unroll
            for (int pt = 0; pt < 4; pt++) {
                f32x4 v = {Zt[pt], St[pt], Dd[pt], Zs[pt]};
                *(f32x4*)&scr[(pt * 16 + n) * 68 + p * 4] = v;
            }
        }
        __syncthreads();
        if (tid < 64) {
            float Z = 0.f, S = 0.f, D = 0.f, Z2 = 0.f;
            #pragma unroll
            for (int p = 0; p < 16; p++) {
                f32x4 v = *(const f32x4*)&scr[tid * 68 + p * 4];
                Z += v[0]; S += v[1]; D += v[2]; Z2 += v[3];
            }
            f32x4 o4 = {Z, S, D, Z2};
            *(f32x4*)&ws[WS_PART + (((size_t)quarter * 8 + b) * 4224 + px0 + tid) * 4] = o4;
        }
    } else if (bx < 304) {
        // ================= rowstats role =================
        float* red = (float*)lds;
        int row  = bx;
        int side = (row >= 152) ? 1 : 0;
        int r    = side ? row - 152 : row;
        const float* src = side ? (t_logit + r * 4225) : (s_logit + r * 16641);

        float z = 0.f, s = 0.f;
        #pragma unroll 4
        for (int k = tid; k < 16641; k += 256) {
            float v = side ? t_resized(src, k) : src[k];
            float e = __expf(v);
            z += e;
            s = fmaf(e, v, s);
        }
        for (int off = 32; off > 0; off >>= 1) { z += __shfl_down(z, off); s += __shfl_down(s, off); }
        if ((tid & 63) == 0) { red[tid >> 6] = z; red[4 + (tid >> 6)] = s; }
        __syncthreads();
        if (tid == 0) {
            float Z = red[0] + red[1] + red[2] + red[3];
            float S = red[4] + red[5] + red[6] + red[7];
            ws[WS_Z + row] = Z;
            atomicAdd(&ws[(side ? WS_E1 : WS_E0) + (r % 19)], S / Z - logf(Z));
        }
    } else {
        // ================= corner pixel (px 4224) role, one block per b ==========
        float* xc  = (float*)lds;          // 128
        float* red = (float*)lds + 128;    // 16
        const int b = bx - 2416;
        if (tid < 128) xc[tid] = s_out[((size_t)b * 128 + tid) * 1089 + 1088];
        __syncthreads();
        float z = 0.f, s = 0.f, d = 0.f, z2 = 0.f;
        #pragma unroll
        for (int rep = 0; rep < 3; rep++) {
            int o = tid + rep * 256;
            const float* Wr = conv_w + (size_t)o * 128;
            float s1 = bias[o];
            for (int cc = 0; cc < 128; cc++) s1 = fmaf(Wr[cc], xc[cc], s1);
            float tv = t_out[((size_t)(b * 768 + o)) * 4225 + 4224];
            float e  = __expf(tv);
            z += e; s = fmaf(e, tv, s); d = fmaf(e, s1, d); z2 += __expf(s1);
        }
        for (int off = 32; off > 0; off >>= 1) {
            z += __shfl_down(z, off); s += __shfl_down(s, off);
            d += __shfl_down(d, off); z2 += __shfl_down(z2, off);
        }
        if ((tid & 63) == 0) {
            int wv = tid >> 6;
            red[wv] = z; red[4 + wv] = s; red[8 + wv] = d; red[12 + wv] = z2;
        }
        __syncthreads();
        if (tid == 0) {
            float Z = red[0] + red[1] + red[2] + red[3];
            float S = red[4] + red[5] + red[6] + red[7];
            float D = red[8] + red[9] + red[10] + red[11];
            float Z2 = red[12] + red[13] + red[14] + red[15];
            float contrib = (S - D) / Z - logf(Z) + logf(Z2);
            atomicAdd(out, contrib * (1.0f / 25958400.0f));
        }
    }
}

// ---------------- mid: Gram (0..527, 512 threads) + pi finalize (528..593) ----------
// Phase 1: resize coords hoisted (k fixed per thread), 19-row loop fully
// unrolled into an independent load batch (vb[19], static idx); exp+store pass.
#define KT 512
#define KP 516
__global__ __launch_bounds__(512)
void k_mid(const float* __restrict__ s_logit, const float* __restrict__ t_logit,
           float* __restrict__ ws, float* __restrict__ out) {
    __shared__ __align__(16) char lds[39296];
    const int tid = threadIdx.x;
    const int bx  = blockIdx.x;

    if (bx < 528) {
        float* pbuf  = (float*)lds;               // [19][516]
        float* rowiz = (float*)(lds + 39216);     // [19]
        int side = (bx >= 264) ? 1 : 0;
        int rm   = side ? bx - 264 : bx;
        int b = rm / 33, kt = rm - b * 33;
        int k0 = kt * KT;

        if (tid < 19) rowiz[tid] = 1.0f / ws[WS_Z + side * 152 + b * 19 + tid];
        __syncthreads();

        const int  k   = k0 + tid;                // tid < 512 = KT
        const bool inb = (k < 16641);

        float vb[19];
        if (side) {
            // hoisted bilinear coords (identical for all 19 rows)
            int y = k / 129, x = k - y * 129;
            int y0 = y >> 1, x0 = x >> 1;
            int y1 = y0 + (y & 1), x1 = x0 + (x & 1);
            float fy = 0.5f * (float)(y & 1), fx = 0.5f * (float)(x & 1);
            int i00 = y0 * 65 + x0, i01 = y0 * 65 + x1;
            int i10 = y1 * 65 + x0, i11 = y1 * 65 + x1;
            const float* Tb = t_logit + (size_t)b * 19 * 4225;
            #pragma unroll
            for (int i = 0; i < 19; i++) {
                if (inb) {
                    const float* Trow = Tb + i * 4225;
                    float v00 = Trow[i00], v01 = Trow[i01];
                    float v10 = Trow[i10], v11 = Trow[i11];
                    float r0 = v00 + fx * (v01 - v00);
                    float r1 = v10 + fx * (v11 - v10);
                    vb[i] = r0 + fy * (r1 - r0);
                } else vb[i] = 0.f;
            }
        } else {
            const float* Sb = s_logit + (size_t)b * 19 * 16641;
            #pragma unroll
            for (int i = 0; i < 19; i++)
                vb[i] = inb ? Sb[(size_t)i * 16641 + k] : 0.f;
        }
        #pragma unroll
        for (int i = 0; i < 19; i++)
            pbuf[i * KP + tid] = inb ? (__expf(vb[i]) * rowiz[i]) : 0.f;
        __syncthreads();

        if (tid < 380) {
            int pr = tid >> 1, h = tid & 1;
            int t = pr, i = 0;
            while (t >= 19 - i) { t -= 19 - i; i++; }
            int j = i + t;
            const float* pi_ = &pbuf[i * KP + h * 256];
            const float* pj_ = &pbuf[j * KP + h * 256];
            float g0 = 0.f, g1 = 0.f, g2 = 0.f, g3 = 0.f;
            #pragma unroll 2
            for (int kl = 0; kl < 256; kl += 16) {
                float4 a0 = *(const float4*)&pi_[kl];      float4 c0 = *(const float4*)&pj_[kl];
                float4 a1 = *(const float4*)&pi_[kl + 4];  float4 c1 = *(const float4*)&pj_[kl + 4];
                float4 a2 = *(const float4*)&pi_[kl + 8];  float4 c2 = *(const float4*)&pj_[kl + 8];
                float4 a3 = *(const float4*)&pi_[kl + 12]; float4 c3 = *(const float4*)&pj_[kl + 12];
                g0 = fmaf(a0.x, c0.x, g0); g0 = fmaf(a0.y, c0.y, g0);
                g0 = fmaf(a0.z, c0.z, g0); g0 = fmaf(a0.w, c0.w, g0);
                g1 = fmaf(a1.x, c1.x, g1); g1 = fmaf(a1.y, c1.y, g1);
                g1 = fmaf(a1.z, c1.z, g1); g1 = fmaf(a1.w, c1.w, g1);
                g2 = fmaf(a2.x, c2.x, g2); g2 = fmaf(a2.y, c2.y, g2);
                g2 = fmaf(a2.z, c2.z, g2); g2 = fmaf(a2.w, c2.w, g2);
                g3 = fmaf(a3.x, c3.x, g3); g3 = fmaf(a3.y, c3.y, g3);
                g3 = fmaf(a3.z, c3.z, g3); g3 = fmaf(a3.w, c3.w, g3);
            }
            float g = (g0 + g1) + (g2 + g3);
            g += __shfl_xor(g, 1);                // combine the two halves
            if (h == 0)
                atomicAdd(&ws[(side ? WS_G1 : WS_G0) + i * 19 + j], g);
        }
    } else {
        // pi finalize: 66 blocks x 512 threads = 33792 = 8 b x 4224 px
        float* red = (float*)lds;
        int gp = (bx - 528) * 512 + tid;
        int b  = gp / 4224;
        int tp = gp - b * 4224;
        float Z = 0.f, S = 0.f, D = 0.f, Z2 = 0.f;
        #pragma unroll
        for (int qq = 0; qq < 4; qq++) {
            f32x4 v = *(const f32x4*)&ws[WS_PART + (((size_t)qq * 8 + b) * 4224 + tp) * 4];
            Z += v[0]; S += v[1]; D += v[2]; Z2 += v[3];
        }
        float contrib = (S - D) / Z - logf(Z) + logf(Z2);
        for (int off = 32; off > 0; off >>= 1) contrib += __shfl_down(contrib, off);
        if ((tid & 63) == 0) red[tid >> 6] = contrib;
        __syncthreads();
        if (tid == 0) {
            float tot = 0.f;
            #pragma unroll
            for (int w = 0; w < 8; w++) tot += red[w];
            atomicAdd(out, tot * (1.0f / 25958400.0f));
        }
    }
}

// ---------------- finalize lo_loss (1 block, 384 threads) ----------------
__global__ void k_final(const float* __restrict__ ws, float* __restrict__ out) {
    __shared__ float Ms[361], Mt[361], ns[19], nt[19];
    __shared__ float red[8];
    int tid = threadIdx.x;
    if (tid < 361) {
        int i = tid / 19, j = tid - i * 19;
        int lo = min(i, j), hi = max(i, j);
        Ms[tid] = (ws[WS_E0 + hi] - ws[WS_G0 + lo * 19 + hi]) * 0.125f;
        Mt[tid] = (ws[WS_E1 + hi] - ws[WS_G1 + lo * 19 + hi]) * 0.125f;
    }
    __syncthreads();
    if (tid < 19) {
        float as = 0.f, at = 0.f;
        for (int j = 0; j < 19; j++) {
            as = fmaf(Ms[tid * 19 + j], Ms[tid * 19 + j], as);
            at = fmaf(Mt[tid * 19 + j], Mt[tid * 19 + j], at);
        }
        ns[tid] = fmaxf(sqrtf(as), 1e-12f);
        nt[tid] = fmaxf(sqrtf(at), 1e-12f);
    }
    __syncthreads();
    float d = 0.f;
    if (tid < 361) {
        int i = tid / 19;
        float v = Ms[tid] / ns[i] - Mt[tid] / nt[i];
        d = v * v;
    }
    for (int off = 32; off > 0; off >>= 1) d += __shfl_down(d, off);
    if ((tid & 63) == 0) red[tid >> 6] = d;
    __syncthreads();
    if (tid == 0) out[1] = red[0] + red[1] + red[2] + red[3] + red[4] + red[5];
}

extern "C" void kernel_launch(void* const* d_in, const int* in_sizes, int n_in,
                              void* d_out, int out_size, void* d_ws, size_t ws_size,
                              hipStream_t stream) {
    const float* s_out   = (const float*)d_in[0];
    const float* t_out   = (const float*)d_in[1];
    const float* t_logit = (const float*)d_in[2];
    const float* s_logit = (const float*)d_in[3];
    const float* conv_w  = (const float*)d_in[4];
    const float* conv_b  = (const float*)d_in[5];
    float* out = (float*)d_out;
    float* ws  = (float*)d_ws;

    k_init<<<dim3(97), dim3(256), 0, stream>>>(conv_w, ws, out);
    k_main<<<dim3(2424), dim3(256), 0, stream>>>(s_out, t_out, conv_w, conv_b,
                                                 s_logit, t_logit, ws, out);
    k_mid<<<dim3(594), dim3(512), 0, stream>>>(s_logit, t_logit, ws, out);
    k_final<<<dim3(1), dim3(384), 0, stream>>>(ws, out);
}